// Round 10
// baseline (188.961 us; speedup 1.0000x reference)
//
#include <hip/hip_runtime.h>
#include <hip/hip_bf16.h>

// B=2, S=2048, E=1024, H=16, HD=KD=VD=64. fp32 I/O, bf16 MFMA internals.
// R10: attn K-loop fully register-double-buffered (K,V,mask prefetched one
// step ahead in explicit A/B register sets, step+=2 unroll) — no per-step
// unhidden load latency, no register rotation. Barrier-free, LDS-free loop.
#define SS 2048
#define EE 1024
#define SCALE 0.125f
#define LOG2E 1.44269504088896f

typedef __attribute__((ext_vector_type(8))) short short8;
typedef __attribute__((ext_vector_type(4))) float float4v;
typedef __attribute__((ext_vector_type(4))) unsigned int uint4v;

__device__ __forceinline__ unsigned short f2bf(float f) {
  unsigned int u = __float_as_uint(f);
  unsigned int lsb = (u >> 16) & 1u;
  u += 0x7fffu + lsb;           // RNE
  return (unsigned short)(u >> 16);
}
__device__ __forceinline__ unsigned int pk2bf(float a, float b) {
  __hip_bfloat162 h = __float22bfloat162_rn(float2{a, b});
  return *reinterpret_cast<unsigned int*>(&h);
}

// ---------------------------------------------------------------------------
// Kernel 1: prep = mask pack (blocks 0..2047) + W3T transpose (2048..2050).
// maskP[((qt*64+step)*64+lane)*8 + j] = bf16(c * mask[qt*16+li][step*32 +
//   (j>>2)*16 + g*4 + (j&3)]), lane = g*16+li (B-frag j-order, folds SCALE*log2e)
// ---------------------------------------------------------------------------
__global__ __launch_bounds__(256) void prep_kernel(
    const float* __restrict__ mask,
    const float* __restrict__ Wq, const float* __restrict__ Wk,
    const float* __restrict__ Wv,
    unsigned short* __restrict__ maskP, unsigned short* __restrict__ W3T)
{
  __shared__ unsigned short t[64 * 65];
  int blk = blockIdx.x;
  int tid = threadIdx.x;
  if (blk < 2048) {
    int idx = blk * 256 + tid;
    int lane = idx & 63, step = (idx >> 6) & 63, qt = idx >> 12;
    int li = lane & 15, g = lane >> 4;
    const float c = SCALE * LOG2E;
    const float* mrow = mask + (size_t)(qt * 16 + li) * SS + step * 32 + g * 4;
    float4 a = *(const float4*)mrow;
    float4 bb = *(const float4*)(mrow + 16);
    uint4v o;
    o.x = pk2bf(a.x * c, a.y * c);
    o.y = pk2bf(a.z * c, a.w * c);
    o.z = pk2bf(bb.x * c, bb.y * c);
    o.w = pk2bf(bb.z * c, bb.w * c);
    *(uint4v*)(maskP + (size_t)idx * 8) = o;
    return;
  }
  int m = blk - 2048;
  const float* W = (m == 0) ? Wq : (m == 1 ? Wk : Wv);
#pragma unroll
  for (int i = 0; i < 16; ++i) {
    int e = tid + i * 256; int d = e >> 6, n = e & 63;
    t[n * 65 + d] = f2bf(W[e]);
  }
  __syncthreads();
  unsigned short* dst = W3T + m * 4096;
#pragma unroll
  for (int i = 0; i < 16; ++i) {
    int e = tid + i * 256; int n = e >> 6, d = e & 63;
    dst[n * 64 + d] = t[n * 65 + d];
  }
}

// ---------------------------------------------------------------------------
// Kernel 2: QKV projection MFMA GEMM. Block = 128 s-rows of one bh, 2 halves.
// Outputs routed through an LDS reorder buffer -> coalesced b128 stores.
//  Kp[bh][step][frag=sb*2+part][lane=g*16+(s&15)][j] = K[s][part*32+g*8+j]
//  Vf[bh][step][nb][lane=(pos>>3)*16+(d&15)][pos&7]  = V[s][d], pos=perm(s&31)
// ---------------------------------------------------------------------------
__global__ __launch_bounds__(256) void qkv_kernel(
    const float* __restrict__ x, const unsigned short* __restrict__ W3T,
    const float* __restrict__ bq, const float* __restrict__ bk,
    const float* __restrict__ bv,
    unsigned short* __restrict__ Q, unsigned short* __restrict__ Kp,
    unsigned short* __restrict__ Vf)
{
  __shared__ __align__(16) unsigned short w3t[192 * 72];
  __shared__ __align__(16) unsigned short xt[64 * 72];
  __shared__ __align__(16) unsigned short ob[12288];   // Q | Kp | Vf half-tile
  __shared__ float sBias[192];
  int tid = threadIdx.x;
  int bh = blockIdx.x >> 4;
  int s0blk = (blockIdx.x & 15) * 128;
  int b = bh >> 4, h = bh & 15;
  int wv = tid >> 6, lane = tid & 63;
  int li = lane & 15, g = lane >> 4;

#pragma unroll
  for (int i = 0; i < 6; ++i) {
    int slot = tid + i * 256;
    int row = slot >> 3, c = slot & 7;
    *(short8*)(w3t + row * 72 + c * 8) = *(const short8*)(W3T + slot * 8);
  }
  if (tid < 192) sBias[tid] = (tid < 64) ? bq[tid] : (tid < 128 ? bk[tid - 64] : bv[tid - 128]);

  for (int half = 0; half < 2; ++half) {
    int s0 = s0blk + half * 64;
    if (half) __syncthreads();        // prior half's ob/xt reads done
    const float* xbase = x + ((size_t)(b * SS + s0)) * EE + h * 64;
#pragma unroll
    for (int it = 0; it < 4; ++it) {
      int flat = tid + it * 256;
      int row = flat >> 4, ch = flat & 15;
      float4 v = *(const float4*)(xbase + (size_t)row * EE + ch * 4);
      uint2 u; u.x = pk2bf(v.x, v.y); u.y = pk2bf(v.z, v.w);
      *(uint2*)(xt + row * 72 + ch * 4) = u;
    }
    __syncthreads();

    int mrow = wv * 16;
    short8 af[2];
#pragma unroll
    for (int ks = 0; ks < 2; ++ks)
      af[ks] = *(const short8*)(xt + (mrow + li) * 72 + ks * 32 + g * 8);

    float4v acc[12];
#pragma unroll
    for (int i = 0; i < 12; ++i) acc[i] = (float4v){0, 0, 0, 0};
#pragma unroll
    for (int ks = 0; ks < 2; ++ks)
#pragma unroll
      for (int nb = 0; nb < 12; ++nb) {
        short8 bfr = *(const short8*)(w3t + (nb * 16 + li) * 72 + ks * 32 + g * 8);
        acc[nb] = __builtin_amdgcn_mfma_f32_16x16x32_bf16(af[ks], bfr, acc[nb], 0, 0, 0);
      }

    // scatter into LDS reorder buffer
#pragma unroll
    for (int nb = 0; nb < 12; ++nb) {
      float bias = sBias[nb * 16 + li];
      int mtx = nb >> 2, sub = nb & 3;
#pragma unroll
      for (int r = 0; r < 4; ++r) {
        unsigned short v = f2bf(acc[nb][r] + bias);
        int sl = mrow + g * 4 + r;         // 0..63 local row
        int stp = sl >> 5, s5 = sl & 31;
        if (mtx == 0) {
          ob[sl * 64 + sub * 16 + li] = v;
        } else if (mtx == 1) {
          int sb = s5 >> 4, lik = s5 & 15;
          int part = sub >> 1;
          int gk = ((sub & 1) << 1) | (li >> 3);
          ob[4096 + stp * 2048 + (sb * 2 + part) * 512 + (gk * 16 + lik) * 8 + (li & 7)] = v;
        } else {
          int pos = ((s5 >> 2) & 3) * 8 + ((s5 >> 4) & 1) * 4 + (s5 & 3);
          ob[8192 + stp * 2048 + sub * 512 + ((pos >> 3) * 16 + li) * 8 + (pos & 7)] = v;
        }
      }
    }
    __syncthreads();

    // coalesced b128 stores: 1536 slots of 8 elems
    unsigned short* Qg = Q + ((size_t)bh * SS + s0) * 64;
    unsigned short* Kg = Kp + (size_t)bh * 131072 + (s0 >> 5) * 2048;
    unsigned short* Vg = Vf + (size_t)bh * 131072 + (s0 >> 5) * 2048;
#pragma unroll
    for (int i = 0; i < 6; ++i) {
      int slot = tid + i * 256;          // 0..1535
      int rgn = slot >> 9, off = (slot & 511) * 8;
      short8 v = *(const short8*)(ob + rgn * 4096 + off);
      unsigned short* dst = (rgn == 0) ? (Qg + off) : (rgn == 1 ? (Kg + off) : (Vg + off));
      *(short8*)dst = v;
    }
  }
}

// ---------------------------------------------------------------------------
// Kernel 3: flash attention, barrier-free, LDS-free, register-double-buffered.
// Wave = 32 q-rows of one bh; grid 512 (2 blocks/CU). K/V/mask for step+1
// prefetched into a second register set; explicit step+=2 unroll (no rotation).
// S^T formulation; den via ones-row MFMA; epilogue O^T->O via wave-private LDS.
// ---------------------------------------------------------------------------
__global__ __launch_bounds__(256) void attn_kernel(
    const unsigned short* __restrict__ Q, const unsigned short* __restrict__ Kp,
    const unsigned short* __restrict__ Vf, const unsigned short* __restrict__ maskP,
    unsigned short* __restrict__ AO)
{
  __shared__ __align__(16) unsigned short tr_all[4 * 32 * 72];  // epilogue only
  int tid = threadIdx.x, wv = tid >> 6, lane = tid & 63;
  int li = lane & 15, g = lane >> 4;
  int wave_id = blockIdx.x * 4 + wv;        // 0..2047
  int bh = wave_id >> 6;
  int q0 = (wave_id & 63) * 32;

  short8 qf[2][2];
#pragma unroll
  for (int t = 0; t < 2; ++t) {
    const unsigned short* Qb = Q + ((size_t)bh * SS + q0 + t * 16 + li) * 64;
    qf[t][0] = *(const short8*)(Qb + g * 8);
    qf[t][1] = *(const short8*)(Qb + 32 + g * 8);
  }

  const unsigned short* Kg = Kp + (size_t)bh * 131072 + lane * 8;
  const unsigned short* Vg = Vf + (size_t)bh * 131072 + lane * 8;
  const unsigned short* Mg0 = maskP + (size_t)(q0 >> 4) * 32768 + lane * 8;
  const unsigned short* Mg1 = Mg0 + 32768;

  unsigned short ov = (li == 0) ? (unsigned short)0x3F80 : (unsigned short)0;
  short8 vones = {(short)ov, (short)ov, (short)ov, (short)ov,
                  (short)ov, (short)ov, (short)ov, (short)ov};

  float4v acc[2][4];
#pragma unroll
  for (int t = 0; t < 2; ++t)
#pragma unroll
    for (int nb = 0; nb < 4; ++nb) acc[t][nb] = (float4v){0, 0, 0, 0};
  float4v accd[2] = {{0, 0, 0, 0}, {0, 0, 0, 0}};

  short8 kfA[4], vfA[4], kfB[4], vfB[4];
  uint4v mA0, mA1, mB0, mB1;

  auto loadSet = [&](int s, short8* kf, short8* vf, uint4v& m0, uint4v& m1) {
#pragma unroll
    for (int i = 0; i < 4; ++i) {
      kf[i] = *(const short8*)(Kg + (size_t)s * 2048 + i * 512);
      vf[i] = *(const short8*)(Vg + (size_t)s * 2048 + i * 512);
    }
    m0 = *(const uint4v*)(Mg0 + (size_t)s * 512);
    m1 = *(const uint4v*)(Mg1 + (size_t)s * 512);
  };

  auto compute = [&](short8* kf, short8* vf, uint4v& m0, uint4v& m1) {
    short8 pf[2];
#pragma unroll
    for (int t = 0; t < 2; ++t) {
      uint4v pw;
#pragma unroll
      for (int sb = 0; sb < 2; ++sb) {
        float4v st = {0, 0, 0, 0};
        st = __builtin_amdgcn_mfma_f32_16x16x32_bf16(kf[sb * 2], qf[t][0], st, 0, 0, 0);
        st = __builtin_amdgcn_mfma_f32_16x16x32_bf16(kf[sb * 2 + 1], qf[t][1], st, 0, 0, 0);
#pragma unroll
        for (int hh = 0; hh < 2; ++hh) {
          unsigned int mm = (t == 0) ? m0[sb * 2 + hh] : m1[sb * 2 + hh];
          float p0 = __builtin_amdgcn_exp2f(st[2 * hh] * __uint_as_float(mm << 16));
          float p1 = __builtin_amdgcn_exp2f(st[2 * hh + 1] * __uint_as_float(mm & 0xffff0000u));
          pw[sb * 2 + hh] = pk2bf(p0, p1);
        }
      }
      pf[t] = *(short8*)&pw;
    }
#pragma unroll
    for (int nb = 0; nb < 4; ++nb) {
      acc[0][nb] = __builtin_amdgcn_mfma_f32_16x16x32_bf16(vf[nb], pf[0], acc[0][nb], 0, 0, 0);
      acc[1][nb] = __builtin_amdgcn_mfma_f32_16x16x32_bf16(vf[nb], pf[1], acc[1][nb], 0, 0, 0);
    }
    accd[0] = __builtin_amdgcn_mfma_f32_16x16x32_bf16(vones, pf[0], accd[0], 0, 0, 0);
    accd[1] = __builtin_amdgcn_mfma_f32_16x16x32_bf16(vones, pf[1], accd[1], 0, 0, 0);
  };

  loadSet(0, kfA, vfA, mA0, mA1);
  for (int step = 0; step < 64; step += 2) {
    loadSet(step + 1, kfB, vfB, mB0, mB1);
    compute(kfA, vfA, mA0, mA1);
    loadSet((step + 2) & 63, kfA, vfA, mA0, mA1);   // wraps to 0 on tail (redundant)
    compute(kfB, vfB, mB0, mB1);
  }

  // den[q=li] in lane li (g=0, reg 0) of accd[t]; epilogue O^T -> O
  unsigned short* tr = tr_all + wv * (32 * 72);
#pragma unroll
  for (int t = 0; t < 2; ++t) {
    float den = __shfl(accd[t][0], li, 64);
    float rd = 1.0f / den;
#pragma unroll
    for (int nb = 0; nb < 4; ++nb) {
      int base = (t * 16 + li) * 72 + nb * 16 + g * 4;
      *(unsigned int*)(tr + base)     = pk2bf(acc[t][nb][0] * rd, acc[t][nb][1] * rd);
      *(unsigned int*)(tr + base + 2) = pk2bf(acc[t][nb][2] * rd, acc[t][nb][3] * rd);
    }
  }
  asm volatile("s_waitcnt lgkmcnt(0)" ::: "memory");

  int b = bh >> 4, h = bh & 15;
  int rrow = lane >> 3, part = lane & 7;
#pragma unroll
  for (int i = 0; i < 4; ++i) {
    int row = i * 8 + rrow;
    short8 o = *(const short8*)(tr + row * 72 + part * 8);
    *(short8*)(AO + ((size_t)(b * SS + q0 + row)) * EE + h * 64 + part * 8) = o;
  }
}

// ---------------------------------------------------------------------------
// Kernel 4: out = AO(4096x1024 bf16) @ Wo(fp32,[k][n]) + bo. 128m x 64n tile,
// BK=64, grid 512. Wo transposed+converted during LDS staging.
// ---------------------------------------------------------------------------
__global__ __launch_bounds__(256) void out_gemm(
    const unsigned short* __restrict__ AO, const float* __restrict__ Wo,
    const float* __restrict__ bo, float* __restrict__ out)
{
  __shared__ __align__(16) unsigned short at[128 * 72];
  __shared__ __align__(16) unsigned short bt[64 * 72];
  int tid = threadIdx.x, wv = tid >> 6, lane = tid & 63;
  int li = lane & 15, g = lane >> 4;
  int m0 = (blockIdx.x >> 4) * 128;
  int n0 = (blockIdx.x & 15) * 64;
  int wm = (wv & 1) * 64, wn = (wv >> 1) * 32;

  const unsigned short* Ag = AO + (size_t)m0 * 1024;
  const float* Bg = Wo + n0;
  int srow = tid >> 3, scol = (tid & 7) * 8;
  int bkrow = tid >> 4, bch = tid & 15;

  short8 apre[4];
  float4 bpre[4];
  auto ldst = [&](int k0) {
#pragma unroll
    for (int i = 0; i < 4; ++i)
      apre[i] = *(const short8*)(Ag + (size_t)(srow + i * 32) * 1024 + k0 + scol);
#pragma unroll
    for (int i = 0; i < 4; ++i)
      bpre[i] = *(const float4*)(Bg + (size_t)(k0 + bkrow + i * 16) * 1024 + bch * 4);
  };

  float4v acc[4][2];
#pragma unroll
  for (int mt = 0; mt < 4; ++mt)
#pragma unroll
    for (int nt = 0; nt < 2; ++nt) acc[mt][nt] = (float4v){0, 0, 0, 0};

  ldst(0);
  for (int k0 = 0; k0 < 1024; k0 += 64) {
    __syncthreads();
#pragma unroll
    for (int i = 0; i < 4; ++i)
      *(short8*)(at + (srow + i * 32) * 72 + scol) = apre[i];
#pragma unroll
    for (int i = 0; i < 4; ++i) {
      int kr = bkrow + i * 16;
      float4 v = bpre[i];
      bt[(bch * 4 + 0) * 72 + kr] = f2bf(v.x);
      bt[(bch * 4 + 1) * 72 + kr] = f2bf(v.y);
      bt[(bch * 4 + 2) * 72 + kr] = f2bf(v.z);
      bt[(bch * 4 + 3) * 72 + kr] = f2bf(v.w);
    }
    int nk = (k0 + 64 < 1024) ? k0 + 64 : 0;
    ldst(nk);
    __syncthreads();
#pragma unroll
    for (int ks = 0; ks < 2; ++ks) {
      short8 afr[4], bfr[2];
#pragma unroll
      for (int mt = 0; mt < 4; ++mt)
        afr[mt] = *(const short8*)(at + (wm + mt * 16 + li) * 72 + ks * 32 + g * 8);
#pragma unroll
      for (int nt = 0; nt < 2; ++nt)
        bfr[nt] = *(const short8*)(bt + (wn + nt * 16 + li) * 72 + ks * 32 + g * 8);
#pragma unroll
      for (int mt = 0; mt < 4; ++mt)
#pragma unroll
        for (int nt = 0; nt < 2; ++nt)
          acc[mt][nt] = __builtin_amdgcn_mfma_f32_16x16x32_bf16(afr[mt], bfr[nt], acc[mt][nt], 0, 0, 0);
    }
  }
#pragma unroll
  for (int nt = 0; nt < 2; ++nt) {
    float bof = bo[n0 + wn + nt * 16 + li];
#pragma unroll
    for (int mt = 0; mt < 4; ++mt)
#pragma unroll
      for (int r = 0; r < 4; ++r)
        out[(size_t)(m0 + wm + mt * 16 + g * 4 + r) * 1024 + n0 + wn + nt * 16 + li] =
            acc[mt][nt][r] + bof;
  }
}

// ---------------------------------------------------------------------------
extern "C" void kernel_launch(void* const* d_in, const int* in_sizes, int n_in,
                              void* d_out, int out_size, void* d_ws, size_t ws_size,
                              hipStream_t stream) {
  const float* x    = (const float*)d_in[0];
  const float* mask = (const float*)d_in[1];
  const float* Wq   = (const float*)d_in[2];
  const float* bq   = (const float*)d_in[3];
  const float* Wk   = (const float*)d_in[4];
  const float* bk   = (const float*)d_in[5];
  const float* Wv   = (const float*)d_in[6];
  const float* bv   = (const float*)d_in[7];
  const float* Wo   = (const float*)d_in[8];
  const float* bo   = (const float*)d_in[9];
  float* out = (float*)d_out;

  unsigned short* ws = (unsigned short*)d_ws;
  unsigned short* Q     = ws;
  unsigned short* Kp    = ws + 4194304;
  unsigned short* Vf    = ws + 8388608;
  unsigned short* AO    = ws + 12582912;
  unsigned short* maskP = ws + 16777216;
  unsigned short* W3T = AO;      // dead until attn writes AO

  prep_kernel<<<2051, 256, 0, stream>>>(mask, Wq, Wk, Wv, maskP, W3T);
  qkv_kernel<<<512, 256, 0, stream>>>(x, W3T, bq, bk, bv, Q, Kp, Vf);
  attn_kernel<<<512, 256, 0, stream>>>(Q, Kp, Vf, maskP, AO);
  out_gemm<<<512, 256, 0, stream>>>(AO, Wo, bo, out);
}